// Round 7
// baseline (88.487 us; speedup 1.0000x reference)
//
#include <hip/hip_runtime.h>
#include <hip/hip_bf16.h>
#include <math.h>

#define NH   8
#define HD   32
#define NP   4
#define EMB  256
#define IMG_H 100
#define IMG_W 100
#define NQ   10000
#define NV   10000
#define BS   4

#define W4S 36   // padded stride for 32-wide rows

#define FENCE() asm volatile("" ::: "memory")

typedef __attribute__((ext_vector_type(8))) short bf16x8;
typedef __attribute__((ext_vector_type(4))) float f32x4;

// ---- ws layout ----------------------------------------------------------------------
#define KT_OFF    0                                   // kt  [BS][NP][NH][HD] f32 16 KB
#define KB_OFF    16384                               // kb  [BS][NP][NH]     f32 512 B
#define BO2_OFF   17408                               // bo2 [EMB]            f32 1 KB
#define WCF_OFF   18432                               // Wcomb f32 [EMB][EMB] 256 KB
#define WCB_OFF   (18432 + 262144)                    // Wcomb bf16           128 KB
#define PREB_OFF  (18432 + 262144 + 131072)           // pre bf16 [BS*NQ][EMB] 20.48 MB
#define WS_FULL   ((size_t)PREB_OFF + (size_t)BS * NQ * EMB * 2)

// ---------------- Kernel 1: sampled keys -> kt = Wq^T(Wk s + bk), kb = bq.(Wk s + bk) -
__global__ __launch_bounds__(64) void k1_keys(
    const float* __restrict__ query, const float* __restrict__ key,
    const float* __restrict__ refp,  const float* __restrict__ Woff,
    const float* __restrict__ boff,  const float* __restrict__ Wk,
    const float* __restrict__ bk,    const float* __restrict__ Wq,
    const float* __restrict__ bq,
    float* __restrict__ kt, float* __restrict__ kb)
{
    int b = blockIdx.x >> 3, h = blockIdx.x & 7;
    __shared__ float q0[HD];
    __shared__ float off[8];
    __shared__ float ks[NP][HD];
    __shared__ float kkl[NP][HD];
    int l = threadIdx.x;

    if (l < HD) q0[l] = query[(size_t)(b * NQ) * EMB + h * HD + l];
    __syncthreads();

    if (l < 8) {
        float s = boff[l];
        #pragma unroll
        for (int d = 0; d < HD; ++d) s += q0[d] * Woff[l * HD + d];
        off[l] = s;
    }
    __syncthreads();

    if (l < HD) {
        float refx = refp[(size_t)(b * NQ) * 2 + 0];
        float refy = refp[(size_t)(b * NQ) * 2 + 1];
        for (int p = 0; p < NP; ++p) {
            float x = refx * IMG_W + off[p * 2 + 0] - 0.5f;
            float y = refy * IMG_H + off[p * 2 + 1] - 0.5f;
            float x0f = floorf(x), y0f = floorf(y);
            int ix0 = (int)x0f, iy0 = (int)y0f;
            float fx = x - x0f, fy = y - y0f;
            float acc = 0.f;
            #pragma unroll
            for (int cy = 0; cy < 2; ++cy)
                #pragma unroll
                for (int cx = 0; cx < 2; ++cx) {
                    int xi = ix0 + cx, yi = iy0 + cy;
                    if ((unsigned)xi < IMG_W && (unsigned)yi < IMG_H) {
                        float wgt = (cx ? fx : 1.f - fx) * (cy ? fy : 1.f - fy);
                        acc += wgt * key[((size_t)b * NV + yi * IMG_W + xi) * EMB + h * HD + l];
                    }
                }
            ks[p][l] = acc;
        }
    }
    __syncthreads();

    #pragma unroll
    for (int t = 0; t < 2; ++t) {
        int idx = l + 64 * t;
        int p = idx >> 5, dout = idx & 31;
        float s = bk[dout];
        #pragma unroll
        for (int d = 0; d < HD; ++d) s += Wk[dout * HD + d] * ks[p][d];
        kkl[p][dout] = s;
    }
    __syncthreads();

    #pragma unroll
    for (int t = 0; t < 2; ++t) {
        int idx = l + 64 * t;
        int p = idx >> 5, d = idx & 31;
        float s = 0.f;
        #pragma unroll
        for (int dd = 0; dd < HD; ++dd) s += Wq[dd * HD + d] * kkl[p][dd];
        kt[((b * NP + p) * NH + h) * HD + d] = s;
    }
    if (l < NP) {
        float s = 0.f;
        #pragma unroll
        for (int dd = 0; dd < HD; ++dd) s += bq[dd] * kkl[l][dd];
        kb[(b * NP + l) * NH + h] = s;
    }
}

// ---------------- Kernel: fold Wv into Wo -> Wcomb (f32 + bf16), bo2 -----------------
__global__ __launch_bounds__(256) void kcomb(
    const float* __restrict__ Wo, const float* __restrict__ Wv,
    const float* __restrict__ bv, const float* __restrict__ bo,
    float* __restrict__ wcf, __hip_bfloat16* __restrict__ wcb,
    float* __restrict__ bo2)
{
    __shared__ float sWv[HD * HD];   // [dd][d]
    __shared__ float sWoR[EMB];
    __shared__ float sws[4];
    int e = blockIdx.x, col = threadIdx.x;
    *(float4*)&sWv[col * 4] = *(const float4*)(Wv + col * 4);
    sWoR[col] = Wo[(size_t)e * EMB + col];
    __syncthreads();

    int h = col >> 5, d = col & 31;
    float s = 0.f;
    #pragma unroll
    for (int dd = 0; dd < HD; ++dd) s += sWoR[h * HD + dd] * sWv[dd * HD + d];
    wcf[(size_t)e * EMB + col] = s;
    wcb[(size_t)e * EMB + col] = __float2bfloat16(s);

    float pb = bv[d] * sWoR[col];
    #pragma unroll
    for (int o = 1; o < 64; o <<= 1) pb += __shfl_xor(pb, o);
    if ((col & 63) == 0) sws[col >> 6] = pb;
    __syncthreads();
    if (col == 0) bo2[e] = bo[e] + sws[0] + sws[1] + sws[2] + sws[3];
}

// ---------------- Kernel 2: 2 queries per wave, interleaved A/B streams --------------
// Block = 256 thr = 4 waves = 8 queries. One __syncthreads (staging). Metadata phase
// uses the FULL wave (lanes<32 -> A, lanes>=32 -> B). Byte offsets precomputed.
template<int BF16OUT>
__global__ __launch_bounds__(256) void k2_main(
    const float* __restrict__ query, const float* __restrict__ value,
    const float* __restrict__ refp,
    const float* __restrict__ Woff, const float* __restrict__ boff,
    const float* __restrict__ kt, const float* __restrict__ kb,
    float* __restrict__ pre, __hip_bfloat16* __restrict__ preb)
{
    __shared__ float sWoff[8 * W4S];
    __shared__ float sboff[8];
    __shared__ float skt[NP * NH * W4S];
    __shared__ float skb[NP * NH];
    __shared__ float qld[8][NH * W4S];
    __shared__ float offs[8][64];
    __shared__ float attnw[8][32];
    __shared__ int   soff4[8][32][4];    // BYTE offsets (incl. batch + head base)
    __shared__ float swgt4[8][32][4];

    int tid = threadIdx.x;
    int b0 = (blockIdx.x * 8) / NQ;      // uniform across block (8 | NQ)

    for (int i = tid; i < 8 * HD; i += 256) sWoff[(i >> 5) * W4S + (i & 31)] = Woff[i];
    if (tid < 8)  sboff[tid] = boff[tid];
    {
        int j = tid * 4;
        *(float4*)&skt[(j >> 5) * W4S + (j & 31)] =
            *(const float4*)(kt + b0 * (NP * NH * HD) + j);
    }
    if (tid < NP * NH) skb[tid] = kb[b0 * (NP * NH) + tid];

    int w = tid >> 6, lane = tid & 63;
    int s0 = w * 2, s1 = w * 2 + 1;
    int gqA = blockIdx.x * 8 + s0;
    int gqB = gqA + 1;

    float4 qvA = *(const float4*)(query + (size_t)gqA * EMB + lane * 4);
    float4 qvB = *(const float4*)(query + (size_t)gqB * EMB + lane * 4);
    {
        int e = lane * 4;
        *(float4*)&qld[s0][(e >> 5) * W4S + (e & 31)] = qvA;
        *(float4*)&qld[s1][(e >> 5) * W4S + (e & 31)] = qvB;
    }
    float refxA = refp[(size_t)gqA * 2 + 0];
    float refyA = refp[(size_t)gqA * 2 + 1];
    float refxB = refp[(size_t)gqB * 2 + 0];
    float refyB = refp[(size_t)gqB * 2 + 1];
    __syncthreads();

    int h = lane >> 3, t = lane & 7;

    // register-cache q[h,:] for both queries
    float qrA[HD], qrB[HD];
    #pragma unroll
    for (int d = 0; d < HD; d += 4) {
        float4 a4 = *(const float4*)&qld[s0][h * W4S + d];
        float4 b4 = *(const float4*)&qld[s1][h * W4S + d];
        qrA[d] = a4.x; qrA[d+1] = a4.y; qrA[d+2] = a4.z; qrA[d+3] = a4.w;
        qrB[d] = b4.x; qrB[d+1] = b4.y; qrB[d+2] = b4.z; qrB[d+3] = b4.w;
    }

    // sampling offsets, shared weight reads
    {
        float sA = sboff[t], sB = sA;
        const float* wr = &sWoff[t * W4S];
        #pragma unroll
        for (int d = 0; d < HD; d += 4) {
            float4 ww = *(const float4*)(wr + d);
            sA += qrA[d] * ww.x + qrA[d+1] * ww.y + qrA[d+2] * ww.z + qrA[d+3] * ww.w;
            sB += qrB[d] * ww.x + qrB[d+1] * ww.y + qrB[d+2] * ww.z + qrB[d+3] * ww.w;
        }
        offs[s0][h * 8 + t] = sA;
        offs[s1][h * 8 + t] = sB;
    }

    // logits via folded keys, shared kt reads
    float plogA[NP], plogB[NP];
    #pragma unroll
    for (int p = 0; p < NP; ++p) {
        const float* kr = &skt[(p * NH + h) * W4S];
        float sA = 0.f, sB = 0.f;
        #pragma unroll
        for (int k = 0; k < 4; ++k) {
            float kv = kr[t + 8 * k];
            sA += qrA[t + 8 * k] * kv;
            sB += qrB[t + 8 * k] * kv;
        }
        plogA[p] = sA; plogB[p] = sB;
    }
    #pragma unroll
    for (int p = 0; p < NP; ++p) {
        plogA[p] += __shfl_xor(plogA[p], 1, 8);
        plogA[p] += __shfl_xor(plogA[p], 2, 8);
        plogA[p] += __shfl_xor(plogA[p], 4, 8);
        plogB[p] += __shfl_xor(plogB[p], 1, 8);
        plogB[p] += __shfl_xor(plogB[p], 2, 8);
        plogB[p] += __shfl_xor(plogB[p], 4, 8);
        float kbv = skb[p * NH + h];
        plogA[p] += kbv; plogB[p] += kbv;
    }
    {
        float mA = fmaxf(fmaxf(plogA[0], plogA[1]), fmaxf(plogA[2], plogA[3]));
        float a0 = __expf(plogA[0]-mA), a1 = __expf(plogA[1]-mA);
        float a2 = __expf(plogA[2]-mA), a3 = __expf(plogA[3]-mA);
        float invA = 1.f / (a0 + a1 + a2 + a3);
        float mB = fmaxf(fmaxf(plogB[0], plogB[1]), fmaxf(plogB[2], plogB[3]));
        float b0e = __expf(plogB[0]-mB), b1 = __expf(plogB[1]-mB);
        float b2 = __expf(plogB[2]-mB), b3 = __expf(plogB[3]-mB);
        float invB = 1.f / (b0e + b1 + b2 + b3);
        if (t < 4) {
            float aA = (t == 0) ? a0 : (t == 1) ? a1 : (t == 2) ? a2 : a3;
            float aB = (t == 0) ? b0e : (t == 1) ? b1 : (t == 2) ? b2 : b3;
            attnw[s0][h * 4 + t] = aA * invA;
            attnw[s1][h * 4 + t] = aB * invB;
        }
    }
    FENCE();

    // metadata: FULL wave — lanes<32 do query A, lanes>=32 do query B
    {
        int side = lane >> 5, ll = lane & 31;
        int slot = w * 2 + side;
        float refx_ = side ? refxB : refxA;
        float refy_ = side ? refyB : refyA;
        int h2 = ll >> 2, p = ll & 3;
        float x = refx_ * IMG_W + offs[slot][h2 * 8 + p * 2 + 0] - 0.5f;
        float y = refy_ * IMG_H + offs[slot][h2 * 8 + p * 2 + 1] - 0.5f;
        float x0f = floorf(x), y0f = floorf(y);
        int ix0 = (int)x0f, iy0 = (int)y0f;
        float fx = x - x0f, fy = y - y0f;
        float aw = attnw[slot][ll];
        float wx1 = fx * aw, wx0 = aw - wx1;
        int bbase = b0 * (NV * EMB) + h2 * HD;
        int   o4[4]; float g4[4];
        #pragma unroll
        for (int c = 0; c < 4; ++c) {
            int cx = c & 1, cy = c >> 1;
            int xi = ix0 + cx, yi = iy0 + cy;
            bool valid = ((unsigned)xi < IMG_W) & ((unsigned)yi < IMG_H);
            int xc = min(max(xi, 0), IMG_W - 1);
            int yc = min(max(yi, 0), IMG_H - 1);
            o4[c] = (bbase + (yc * IMG_W + xc) * EMB) * 4;   // bytes
            float wv = (cx ? wx1 : wx0) * (cy ? fy : 1.f - fy);
            g4[c] = valid ? wv : 0.f;
        }
        int4   ov = {o4[0], o4[1], o4[2], o4[3]};
        float4 gv = {g4[0], g4[1], g4[2], g4[3]};
        *(int4*)&soff4[slot][ll][0]   = ov;
        *(float4*)&swgt4[slot][ll][0] = gv;
    }
    FENCE();

    // gather: interleaved A/B, 8 loads in flight per p-iteration
    {
        int hh = lane >> 3, cg = lane & 7;
        unsigned co = cg * 16;               // byte offset within head row
        const char* vb = (const char*)value;
        float4 accA = {0.f,0.f,0.f,0.f}, accB = {0.f,0.f,0.f,0.f};
        #pragma unroll
        for (int p = 0; p < NP; ++p) {
            int hp = hh * 4 + p;
            int4   oA = *(const int4*)&soff4[s0][hp][0];
            float4 gA = *(const float4*)&swgt4[s0][hp][0];
            int4   oB = *(const int4*)&soff4[s1][hp][0];
            float4 gB = *(const float4*)&swgt4[s1][hp][0];
            float4 a0 = *(const float4*)(vb + (unsigned)oA.x + co);
            float4 a1 = *(const float4*)(vb + (unsigned)oA.y + co);
            float4 a2 = *(const float4*)(vb + (unsigned)oA.z + co);
            float4 a3 = *(const float4*)(vb + (unsigned)oA.w + co);
            float4 b0v = *(const float4*)(vb + (unsigned)oB.x + co);
            float4 b1v = *(const float4*)(vb + (unsigned)oB.y + co);
            float4 b2v = *(const float4*)(vb + (unsigned)oB.z + co);
            float4 b3v = *(const float4*)(vb + (unsigned)oB.w + co);
            accA.x += gA.x*a0.x + gA.y*a1.x + gA.z*a2.x + gA.w*a3.x;
            accA.y += gA.x*a0.y + gA.y*a1.y + gA.z*a2.y + gA.w*a3.y;
            accA.z += gA.x*a0.z + gA.y*a1.z + gA.z*a2.z + gA.w*a3.z;
            accA.w += gA.x*a0.w + gA.y*a1.w + gA.z*a2.w + gA.w*a3.w;
            accB.x += gB.x*b0v.x + gB.y*b1v.x + gB.z*b2v.x + gB.w*b3v.x;
            accB.y += gB.x*b0v.y + gB.y*b1v.y + gB.z*b2v.y + gB.w*b3v.y;
            accB.z += gB.x*b0v.z + gB.y*b1v.z + gB.z*b2v.z + gB.w*b3v.z;
            accB.w += gB.x*b0v.w + gB.y*b1v.w + gB.z*b2v.w + gB.w*b3v.w;
        }
        int cb = cg * 4;
        if (BF16OUT) {
            __hip_bfloat16 pkA[4], pkB[4];
            pkA[0] = __float2bfloat16(accA.x); pkA[1] = __float2bfloat16(accA.y);
            pkA[2] = __float2bfloat16(accA.z); pkA[3] = __float2bfloat16(accA.w);
            pkB[0] = __float2bfloat16(accB.x); pkB[1] = __float2bfloat16(accB.y);
            pkB[2] = __float2bfloat16(accB.z); pkB[3] = __float2bfloat16(accB.w);
            *(ushort4*)((unsigned short*)preb + (size_t)gqA * EMB + hh * HD + cb) =
                *(const ushort4*)&pkA[0];
            *(ushort4*)((unsigned short*)preb + (size_t)gqB * EMB + hh * HD + cb) =
                *(const ushort4*)&pkB[0];
        } else {
            *(float4*)(pre + (size_t)gqA * EMB + hh * HD + cb) = accA;
            *(float4*)(pre + (size_t)gqB * EMB + hh * HD + cb) = accB;
        }
    }
}

// ---------------- Kernel 3a: MFMA bf16 GEMM out = preb @ Wcomb^T + bo2 + residual ----
__global__ __launch_bounds__(256) void k3_mfma(
    const __hip_bfloat16* __restrict__ preb, const __hip_bfloat16* __restrict__ wcb,
    float* __restrict__ outp, const float* __restrict__ query,
    const float* __restrict__ bo2)
{
    int w = threadIdx.x >> 6, lane = threadIdx.x & 63;
    size_t m0 = (size_t)blockIdx.x * 64;
    int n0 = w * 64;
    int lr = lane & 15, lg = lane >> 4;

    const short* pa = (const short*)preb;
    const short* pb = (const short*)wcb;

    f32x4 acc[4][4];
    #pragma unroll
    for (int mt = 0; mt < 4; ++mt)
        #pragma unroll
        for (int nt = 0; nt < 4; ++nt) acc[mt][nt] = (f32x4){0.f, 0.f, 0.f, 0.f};

    #pragma unroll
    for (int k0 = 0; k0 < EMB; k0 += 32) {
        bf16x8 af[4], bf[4];
        #pragma unroll
        for (int mt = 0; mt < 4; ++mt)
            af[mt] = *(const bf16x8*)(pa + (m0 + mt * 16 + lr) * EMB + k0 + lg * 8);
        #pragma unroll
        for (int nt = 0; nt < 4; ++nt)
            bf[nt] = *(const bf16x8*)(pb + (size_t)(n0 + nt * 16 + lr) * EMB + k0 + lg * 8);
        #pragma unroll
        for (int mt = 0; mt < 4; ++mt)
            #pragma unroll
            for (int nt = 0; nt < 4; ++nt)
                acc[mt][nt] = __builtin_amdgcn_mfma_f32_16x16x32_bf16(
                    af[mt], bf[nt], acc[mt][nt], 0, 0, 0);
    }

    float bov[4];
    #pragma unroll
    for (int nt = 0; nt < 4; ++nt) bov[nt] = bo2[n0 + nt * 16 + lr];

    #pragma unroll
    for (int mt = 0; mt < 4; ++mt)
        #pragma unroll
        for (int q = 0; q < 4; ++q) {
            size_t row = m0 + mt * 16 + lg * 4 + q;
            const float* qrow = query + row * EMB;
            float* orow = outp + row * EMB;
            #pragma unroll
            for (int nt = 0; nt < 4; ++nt) {
                int col = n0 + nt * 16 + lr;
                orow[col] = acc[mt][nt][q] + bov[nt] + qrow[col];
            }
        }
}

// ---------------- Kernel 3b: f32 fallback (in-place over d_out, Wcomb f32) -----------
__global__ __launch_bounds__(256) void k3_gemm(
    const float* __restrict__ pre, float* __restrict__ outp,
    const float* __restrict__ query, const float* __restrict__ wcf,
    const float* __restrict__ bo2)
{
    __shared__ float As[64 * EMB];
    int tid = threadIdx.x;
    size_t r0 = (size_t)blockIdx.x * 64;
    {
        const float4* src = (const float4*)(pre + r0 * EMB);
        float4* dst = (float4*)As;
        for (int i = tid; i < 64 * EMB / 4; i += 256) dst[i] = src[i];
    }
    __syncthreads();

    int w = tid >> 6, lane = tid & 63;
    int rb = w * 16;
    float acc[16][4];
    #pragma unroll
    for (int r = 0; r < 16; ++r)
        #pragma unroll
        for (int j = 0; j < 4; ++j) acc[r][j] = 0.f;

    for (int kc = 0; kc < EMB / 4; ++kc) {
        float4 wreg[4];
        #pragma unroll
        for (int j = 0; j < 4; ++j)
            wreg[j] = *(const float4*)&wcf[(size_t)(lane + 64 * j) * EMB + kc * 4];
        #pragma unroll
        for (int r = 0; r < 16; ++r) {
            float4 a = *(const float4*)&As[(rb + r) * EMB + kc * 4];
            #pragma unroll
            for (int j = 0; j < 4; ++j)
                acc[r][j] += a.x * wreg[j].x + a.y * wreg[j].y
                           + a.z * wreg[j].z + a.w * wreg[j].w;
        }
    }

    #pragma unroll
    for (int r = 0; r < 16; ++r) {
        size_t row = r0 + rb + r;
        #pragma unroll
        for (int j = 0; j < 4; ++j) {
            int c = lane + 64 * j;
            outp[row * EMB + c] = acc[r][j] + bo2[c] + query[row * EMB + c];
        }
    }
}

extern "C" void kernel_launch(void* const* d_in, const int* in_sizes, int n_in,
                              void* d_out, int out_size, void* d_ws, size_t ws_size,
                              hipStream_t stream) {
    const float* query = (const float*)d_in[0];
    const float* key   = (const float*)d_in[1];
    const float* value = (const float*)d_in[2];
    const float* refp  = (const float*)d_in[3];
    const float* Wq   = (const float*)d_in[4];
    const float* bq   = (const float*)d_in[5];
    const float* Wk   = (const float*)d_in[6];
    const float* bk   = (const float*)d_in[7];
    const float* Wv   = (const float*)d_in[8];
    const float* bv   = (const float*)d_in[9];
    const float* Woff = (const float*)d_in[10];
    const float* boff = (const float*)d_in[11];
    const float* Wo   = (const float*)d_in[12];
    const float* bo   = (const float*)d_in[13];
    (void)in_sizes; (void)n_in; (void)out_size;

    float* out = (float*)d_out;
    char*  ws  = (char*)d_ws;
    float* kt  = (float*)(ws + KT_OFF);
    float* kb  = (float*)(ws + KB_OFF);
    float* bo2 = (float*)(ws + BO2_OFF);
    float* wcf = (float*)(ws + WCF_OFF);
    __hip_bfloat16* wcb = (__hip_bfloat16*)(ws + WCB_OFF);

    k1_keys<<<BS * NH, 64, 0, stream>>>(query, key, refp, Woff, boff, Wk, bk,
                                        Wq, bq, kt, kb);
    kcomb<<<EMB, 256, 0, stream>>>(Wo, Wv, bv, bo, wcf, wcb, bo2);

    if (ws_size >= WS_FULL) {
        __hip_bfloat16* preb = (__hip_bfloat16*)(ws + PREB_OFF);
        k2_main<1><<<BS * NQ / 8, 256, 0, stream>>>(query, value, refp, Woff, boff,
                                                    kt, kb, nullptr, preb);
        k3_mfma<<<BS * NQ / 64, 256, 0, stream>>>(preb, wcb, out, query, bo2);
    } else {
        k2_main<0><<<BS * NQ / 8, 256, 0, stream>>>(query, value, refp, Woff, boff,
                                                    kt, kb, out, nullptr);
        k3_gemm<<<BS * NQ / 64, 256, 0, stream>>>(out, out, query, wcf, bo2);
    }
}